// Round 6
// baseline (487.906 us; speedup 1.0000x reference)
//
#include <hip/hip_runtime.h>
#include <hip/hip_fp16.h>
#include <cstdint>
#include <cmath>

#define TOKENS  16384
#define HIDDEN  4096
#define NEXP    256
#define TOPK    8
#define KDROP   4   /* n_group - topk_group */

typedef _Float16 f16x8  __attribute__((ext_vector_type(8)));
typedef float    f32x16 __attribute__((ext_vector_type(16)));
typedef float    f32x4  __attribute__((ext_vector_type(4)));

#define LO_SCALE 2048.0f          /* 2^11 */
#define LO_INV   (1.0f/2048.0f)

// ws layout (bytes):
//   [0, 16777216)            gates0 fp32 [TOKENS][NEXP]   (K-half 0)
//   [16777216, +16777216)    gates1 fp32 [TOKENS][NEXP]   (K-half 1)
//   [33554432, +2097152)     w_h  f16 chunk-array
//   [35651584, +2097152)     w_l  f16 chunk-array (scaled by 2^11)
#define WS_G0_OFF 0
#define WS_G1_OFF 16777216
#define WS_WH_OFF 33554432
#define WS_WL_OFF 35651584

// direct global->LDS (16 B per lane, no VGPR round-trip)
static __device__ __forceinline__ void gload16(const float* g, float* l)
{
    __builtin_amdgcn_global_load_lds(
        (const __attribute__((address_space(1))) unsigned int*)g,
        (__attribute__((address_space(3))) unsigned int*)l, 16, 0, 0);
}

// ---------------------------------------------------------------------------
// Pre-kernel: split w (fp32) into f16 hi / (lo*2^11) stored in MFMA-frag
// chunk order: chunk (e,k8grp) -> cid = ((kc*2+s)*8 + e/32)*64 + hl*32 + e%32
// where kc=k/32, s=(k/16)%2, hl=(k/8)%2.  Each chunk = 8 consecutive k f16.
// ---------------------------------------------------------------------------
__global__ __launch_bounds__(256)
void wsplit(const float* __restrict__ w, _Float16* __restrict__ wh,
            _Float16* __restrict__ wl)
{
    const int idx = blockIdx.x * 256 + threadIdx.x;   // 0..131071
    const int e   = idx >> 9;                         // expert 0..255
    const int kg8 = idx & 511;                        // 8-k group
    const float4* p = (const float4*)(w + (size_t)e * HIDDEN + kg8 * 8);
    float4 f0 = p[0], f1 = p[1];
    float v[8] = {f0.x, f0.y, f0.z, f0.w, f1.x, f1.y, f1.z, f1.w};
    f16x8 hi, lo;
    #pragma unroll
    for (int i = 0; i < 8; ++i) {
        _Float16 h = (_Float16)v[i];
        hi[i] = h;
        lo[i] = (_Float16)((v[i] - (float)h) * LO_SCALE);
    }
    const int kc = kg8 >> 2, s = (kg8 >> 1) & 1, hl = kg8 & 1;
    const int cid = ((kc * 2 + s) * 8 + (e >> 5)) * 64 + hl * 32 + (e & 31);
    ((f16x8*)wh)[cid] = hi;
    ((f16x8*)wl)[cid] = lo;
}

// ---------------------------------------------------------------------------
// GEMM: gates_half = x @ W^T via split-f16 MFMA, A staged RAW via
// global_load_lds (16 B), hi/lo conversion done on read in the MFMA shadow.
// Grid 1024 = tok-tile(256) x exp-half(2) x K-half(2); block = 256 thr
// (4 waves) = 64 tok x 128 exp x one K-half; wave = 64 tok x 32 exp
// (acc 64 AGPR). 4 blocks/CU resident (4 waves/SIMD), 4 INDEPENDENT
// barrier groups per CU -> one block's barrier drain overlaps another's
// MFMA cluster.
// LDS A layout (fp32, 8 KB/buf): slot = ((s*2+r)*2+jh)*64 + l holds
// x[tok0 + r*32 + (l&31)][kc*32 + s*16 + (l>>5)*8 + jh*4 .. +3]
//   - gload_lds dest = tid*16 bytes (linear, wave-uniform base + lane*16 OK)
//   - frag read = 2 x b128 at 16 B lane stride (conflict-free both sides)
// B frags register-loaded same-iter from chunk-ordered L2-resident wh/wl.
// ---------------------------------------------------------------------------
__global__ __launch_bounds__(256, 4)
void gemm_split(const float* __restrict__ x, const _Float16* __restrict__ wh,
                const _Float16* __restrict__ wl,
                float* __restrict__ g0, float* __restrict__ g1)
{
    __shared__ float A32[2][2048];   // 2 x 8 KB raw fp32 A tiles

    const int tid  = threadIdx.x;
    const int w    = tid >> 6;           // wave 0..3
    const int lane = tid & 63;

    const int bid  = blockIdx.x;         // 0..1023
    const int y    = bid & 1;            // K-half
    const int eh   = (bid >> 1) & 1;     // expert half
    const int tok0 = (bid >> 2) * 64;
    const int kcg0 = y * 64;             // first 32-k chunk of this K-half
    const int we   = eh * 4 + w;         // 32-expert group 0..7
    float* gates_half = y ? g1 : g0;

    // staging decode for slots tid (s=0) and tid+256 (s=1)
    const int sl   = tid & 63;
    const int sjh  = (tid >> 6) & 1;
    const int sr   = (tid >> 7) & 1;
    const int stok = sr * 32 + (sl & 31);
    const int koff = ((sl >> 5)) * 8 + sjh * 4;
    const float* xb = x + (size_t)(tok0 + stok) * HIDDEN + (size_t)kcg0 * 32 + koff;

    const f16x8* whc = (const f16x8*)wh;
    const f16x8* wlc = (const f16x8*)wl;

    f32x16 accH[2] = {};   // hi*hi                 [row-tile r]
    f32x16 accX[2] = {};   // lo*hi + hi*lo (x 2^11)

    // ---- prologue: stage A(0) -> LDS[0]
    gload16(xb,      &A32[0][tid * 4]);
    gload16(xb + 16, &A32[0][(tid + 256) * 4]);
    asm volatile("s_waitcnt vmcnt(0)" ::: "memory");
    __syncthreads();

    #pragma unroll 2
    for (int kc = 0; kc < 64; ++kc) {
        const int cur = kc & 1;

        // ---- stage A(kc+1) into the other buffer (direct to LDS)
        if (kc + 1 < 64) {
            const float* gp = xb + (size_t)(kc + 1) * 32;
            gload16(gp,      &A32[cur ^ 1][tid * 4]);
            gload16(gp + 16, &A32[cur ^ 1][(tid + 256) * 4]);
        }

        // ---- B frags for this iter (L2-resident chunk array)
        f16x8 bh[2], bl[2];
        {
            const int kcg = kcg0 + kc;
            #pragma unroll
            for (int s = 0; s < 2; ++s) {
                bh[s] = whc[((kcg * 2 + s) * 8 + we) * 64 + lane];
                bl[s] = wlc[((kcg * 2 + s) * 8 + we) * 64 + lane];
            }
        }

        // ---- compute: read raw fp32 frags, convert hi/lo in-reg, MFMA
        #pragma unroll
        for (int s = 0; s < 2; ++s) {
            f16x8 ah0, al0, ah1, al1;
            #pragma unroll
            for (int r = 0; r < 2; ++r) {
                f32x4 u0 = *(const f32x4*)&A32[cur][(((s * 2 + r) * 2 + 0) * 64 + lane) * 4];
                f32x4 u1 = *(const f32x4*)&A32[cur][(((s * 2 + r) * 2 + 1) * 64 + lane) * 4];
                f16x8 hi, lo;
                #pragma unroll
                for (int i = 0; i < 4; ++i) {
                    _Float16 h = (_Float16)u0[i];
                    hi[i] = h;
                    lo[i] = (_Float16)((u0[i] - (float)h) * LO_SCALE);
                }
                #pragma unroll
                for (int i = 0; i < 4; ++i) {
                    _Float16 h = (_Float16)u1[i];
                    hi[i + 4] = h;
                    lo[i + 4] = (_Float16)((u1[i] - (float)h) * LO_SCALE);
                }
                if (r == 0) { ah0 = hi; al0 = lo; }
                else        { ah1 = hi; al1 = lo; }
            }

            __builtin_amdgcn_s_setprio(1);
            accH[0] = __builtin_amdgcn_mfma_f32_32x32x16_f16(ah0, bh[s], accH[0], 0, 0, 0);
            accH[1] = __builtin_amdgcn_mfma_f32_32x32x16_f16(ah1, bh[s], accH[1], 0, 0, 0);
            accX[0] = __builtin_amdgcn_mfma_f32_32x32x16_f16(al0, bh[s], accX[0], 0, 0, 0);
            accX[1] = __builtin_amdgcn_mfma_f32_32x32x16_f16(al1, bh[s], accX[1], 0, 0, 0);
            accX[0] = __builtin_amdgcn_mfma_f32_32x32x16_f16(ah0, bl[s], accX[0], 0, 0, 0);
            accX[1] = __builtin_amdgcn_mfma_f32_32x32x16_f16(ah1, bl[s], accX[1], 0, 0, 0);
            __builtin_amdgcn_s_setprio(0);
        }

        __syncthreads();
    }

    // ---- epilogue: combine hi + lo*2^-11, plain stores
    const int col   = lane & 31;
    const int rbase = 4 * (lane >> 5);
    #pragma unroll
    for (int r = 0; r < 2; ++r) {
        float* gp = gates_half + (size_t)(tok0 + r * 32) * NEXP + eh * 128 + w * 32 + col;
        #pragma unroll
        for (int reg = 0; reg < 16; ++reg) {
            const int row = (reg & 3) + 8 * (reg >> 2) + rbase;
            gp[(size_t)row * NEXP] = accH[r][reg] + accX[r][reg] * LO_INV;
        }
    }
}

// ---------------------------------------------------------------------------
// Gating epilogue: one wave per token; sums the two K-half gate buffers.
// All-register top-k (no dynamic array indexing -> no scratch).
// ---------------------------------------------------------------------------
__device__ __forceinline__ unsigned ordkey(float f) {
    unsigned u = __float_as_uint(f);
    return (u & 0x80000000u) ? ~u : (u | 0x80000000u);  // monotone float->uint
}

__global__ __launch_bounds__(256, 4)
void gate_epilogue(const float* __restrict__ g0,
                   const float* __restrict__ g1,
                   const float* __restrict__ bias,
                   float* __restrict__ out)
{
    const int tid  = threadIdx.x;
    const int wv   = tid >> 6;
    const int lane = tid & 63;
    const int t    = blockIdx.x * 4 + wv;

    float4 ga = ((const float4*)(g0 + (size_t)t * NEXP))[lane];
    float4 gb = ((const float4*)(g1 + (size_t)t * NEXP))[lane];
    float4 bv = ((const float4*)bias)[lane];
    float4 gv = make_float4(ga.x + gb.x, ga.y + gb.y, ga.z + gb.z, ga.w + gb.w);

    float sig0 = 1.0f / (1.0f + expf(-gv.x));
    float sig1 = 1.0f / (1.0f + expf(-gv.y));
    float sig2 = 1.0f / (1.0f + expf(-gv.z));
    float sig3 = 1.0f / (1.0f + expf(-gv.w));
    float sc0 = sig0 + bv.x, sc1 = sig1 + bv.y;
    float sc2 = sig2 + bv.z, sc3 = sig3 + bv.w;

    // top-2 of my 4 scores
    float m1 = fmaxf(sc0, sc1);
    float m2 = fminf(sc0, sc1);
    if (sc2 > m1) { m2 = m1; m1 = sc2; } else m2 = fmaxf(m2, sc2);
    if (sc3 > m1) { m2 = m1; m1 = sc3; } else m2 = fmaxf(m2, sc3);
    // merge across the 8 lanes of this group (group = lane>>3, 32 experts)
    #pragma unroll
    for (int off = 1; off < 8; off <<= 1) {
        float o1 = __shfl_xor(m1, off);
        float o2 = __shfl_xor(m2, off);
        float nm1 = fmaxf(m1, o1);
        float nm2 = fmaxf(fminf(m1, o1), fmaxf(m2, o2));
        m1 = nm1; m2 = nm2;
    }
    float gsum = m1 + m2;
    float gs[8];
    #pragma unroll
    for (int gi = 0; gi < 8; ++gi) gs[gi] = __shfl(gsum, gi * 8);

    // keep the KDROP smallest groups (tie -> lower index), faithful to ref
    int keepmask = 0;
    #pragma unroll
    for (int g = 0; g < 8; ++g) {
        int rank = 0;
        #pragma unroll
        for (int h = 0; h < 8; ++h)
            rank += (gs[h] < gs[g]) || (gs[h] == gs[g] && h < g);
        if (rank < KDROP) keepmask |= (1 << g);
    }
    const bool kept = (keepmask >> (lane >> 3)) & 1;

    // lexicographic (value asc, index asc) keys; masked entries = +0.0
    const unsigned ib = (unsigned)(lane * 4);
    unsigned long long k0 = ((unsigned long long)ordkey(kept ? sc0 : 0.0f) << 32) | (ib + 0);
    unsigned long long k1 = ((unsigned long long)ordkey(kept ? sc1 : 0.0f) << 32) | (ib + 1);
    unsigned long long k2 = ((unsigned long long)ordkey(kept ? sc2 : 0.0f) << 32) | (ib + 2);
    unsigned long long k3 = ((unsigned long long)ordkey(kept ? sc3 : 0.0f) << 32) | (ib + 3);

    float ssum = 0.0f, myval = 0.0f;
    int myidx = 0;
    #pragma unroll
    for (int r = 0; r < TOPK; ++r) {
        unsigned long long kmin = k0 < k1 ? k0 : k1;
        if (k2 < kmin) kmin = k2;
        if (k3 < kmin) kmin = k3;
        #pragma unroll
        for (int off = 32; off >= 1; off >>= 1) {
            unsigned long long o = __shfl_xor(kmin, off);
            if (o < kmin) kmin = o;
        }
        const int id   = (int)(kmin & 0xffffffffull);
        const int src  = id >> 2;   // owning lane (wave-uniform)
        const int slot = id & 3;    // wave-uniform
        float vsrc = (slot == 0) ? sig0 : (slot == 1) ? sig1
                   : (slot == 2) ? sig2 : sig3;
        float v = __shfl(vsrc, src);
        ssum += v;
        if (lane == r) { myidx = id; myval = v; }
        const bool mine = (lane == src);
        if (mine && slot == 0) k0 = ~0ull;
        if (mine && slot == 1) k1 = ~0ull;
        if (mine && slot == 2) k2 = ~0ull;
        if (mine && slot == 3) k3 = ~0ull;
    }

    if (lane < TOPK) {
        out[(size_t)t * TOPK + lane] = (float)myidx;                      // inds
        out[(size_t)TOKENS * TOPK + (size_t)t * TOPK + lane] =
            myval / (ssum + 1e-20f) * 2.5f;                               // sel
    }
}

// ---------------------------------------------------------------------------
extern "C" void kernel_launch(void* const* d_in, const int* in_sizes, int n_in,
                              void* d_out, int out_size, void* d_ws, size_t ws_size,
                              hipStream_t stream)
{
    const float* x    = (const float*)d_in[0];
    const float* w    = (const float*)d_in[1];
    const float* bias = (const float*)d_in[2];
    float* out = (float*)d_out;

    float*     g0 = (float*)((char*)d_ws + WS_G0_OFF);
    float*     g1 = (float*)((char*)d_ws + WS_G1_OFF);
    _Float16*  wh = (_Float16*)((char*)d_ws + WS_WH_OFF);
    _Float16*  wl = (_Float16*)((char*)d_ws + WS_WL_OFF);

    // split w into chunk-ordered f16 hi/lo
    wsplit<<<dim3(512), dim3(256), 0, stream>>>(w, wh, wl);
    // split-f16 MFMA GEMM, global_load_lds A staging, convert-on-read
    gemm_split<<<dim3(1024), dim3(256), 0, stream>>>(x, wh, wl, g0, g1);
    // gating epilogue sums the halves
    gate_epilogue<<<dim3(TOKENS / 4), dim3(256), 0, stream>>>(g0, g1, bias, out);
}